// Round 1
// baseline (670.693 us; speedup 1.0000x reference)
//
#include <hip/hip_runtime.h>

typedef unsigned short u16;
typedef __bf16 bf16x8 __attribute__((ext_vector_type(8)));
typedef float f32x4 __attribute__((ext_vector_type(4)));

// ---------- helpers ----------
__device__ __forceinline__ u16 f2bf(float f) {
  union { float f; unsigned u; } v; v.f = f;
  return (u16)((v.u + 0x7fffu + ((v.u >> 16) & 1u)) >> 16);   // RNE
}

#define GLDS16(g, l)                                                          \
  __builtin_amdgcn_global_load_lds(                                           \
      (const __attribute__((address_space(1))) void*)(g),                     \
      (__attribute__((address_space(3))) void*)(l), 16, 0, 0)

// ---------- sizes ----------
#define NTOK 4096     // B*T
#define DIM  768
#define HID  1536
#define NEXP 8
#define NEXP1 9       // 8 routed + 1 shared

// ---------- f32 -> bf16 elementwise (x) ----------
__global__ __launch_bounds__(256) void k_cvt_x(const float* __restrict__ src,
                                               u16* __restrict__ dst, int n4) {
  const int i = blockIdx.x * 256 + threadIdx.x;
  if (i >= n4) return;
  const float4 v = ((const float4*)src)[i];
  ushort4 o;
  o.x = f2bf(v.x); o.y = f2bf(v.y); o.z = f2bf(v.z); o.w = f2bf(v.w);
  ((ushort4*)dst)[i] = o;
}

// ---------- batched transpose f32[R][C] -> bf16[C][R] ----------
__global__ __launch_bounds__(256) void k_tr(const float* __restrict__ src,
                                            u16* __restrict__ dst, int R, int C) {
  __shared__ u16 tile[32][33];
  const size_t bo = (size_t)blockIdx.z * R * C;
  src += bo; dst += bo;
  const int c0 = blockIdx.x * 32, r0 = blockIdx.y * 32;
  const int tx = threadIdx.x, ty = threadIdx.y;
  #pragma unroll
  for (int i = 0; i < 32; i += 8)
    tile[ty + i][tx] = f2bf(src[(size_t)(r0 + ty + i) * C + c0 + tx]);
  __syncthreads();
  #pragma unroll
  for (int i = 0; i < 32; i += 8)
    dst[(size_t)(c0 + ty + i) * R + r0 + tx] = tile[tx][ty + i];
}

// ---------- router: probs + combine weights ----------
__global__ __launch_bounds__(64) void k_router(const float* __restrict__ x,
                                               const float* __restrict__ rw,
                                               float* __restrict__ probs,
                                               float* __restrict__ cw) {
  const int t = blockIdx.x;
  const int lane = threadIdx.x;
  const float* xr = x + (size_t)t * DIM;
  float acc[NEXP] = {0, 0, 0, 0, 0, 0, 0, 0};
  for (int d = lane; d < DIM; d += 64) {
    const float xv = xr[d];
    #pragma unroll
    for (int e = 0; e < NEXP; e++) acc[e] += xv * rw[e * DIM + d];
  }
  #pragma unroll
  for (int e = 0; e < NEXP; e++)
    #pragma unroll
    for (int s = 32; s > 0; s >>= 1) acc[e] += __shfl_xor(acc[e], s, 64);
  if (lane == 0) {
    float mx = acc[0];
    #pragma unroll
    for (int e = 1; e < NEXP; e++) mx = fmaxf(mx, acc[e]);
    float p[NEXP], sum = 0.f;
    #pragma unroll
    for (int e = 0; e < NEXP; e++) { p[e] = expf(acc[e] - mx); sum += p[e]; }
    const float inv = 1.f / sum;
    #pragma unroll
    for (int e = 0; e < NEXP; e++) p[e] *= inv;
    #pragma unroll
    for (int e = 0; e < NEXP; e++) probs[(size_t)t * NEXP + e] = p[e];
    // top-2, first-occurrence on ties (matches lax.top_k)
    int i1 = 0;
    #pragma unroll
    for (int e = 1; e < NEXP; e++) if (p[e] > p[i1]) i1 = e;
    int i2 = (i1 == 0) ? 1 : 0;
    #pragma unroll
    for (int e = 0; e < NEXP; e++) if (e != i1 && p[e] > p[i2]) i2 = e;
    const float s2 = 1.f / (p[i1] + p[i2]);
    float c[NEXP1];
    #pragma unroll
    for (int e = 0; e < NEXP1; e++) c[e] = 0.f;
    c[i1] = p[i1] * s2;
    c[i2] = p[i2] * s2;
    c[NEXP] = 1.f;                       // shared expert always on, weight 1
    #pragma unroll
    for (int e = 0; e < NEXP1; e++) cw[(size_t)t * NEXP1 + e] = c[e];
  }
}

// ---------- gemm1: hidden = bf16( cw * silu(x*w1) * (x*w2) ) ----------
// A = xb [NTOK][DIM], B^T rows = w1t/w2t [HID][DIM].  Tile 128x64, BK=32,
// 4 waves (2x2), wave tile 64x32 -> frags m=0..3, n=0..1, dual accumulators.
__global__ __launch_bounds__(256) void k_gemm1(const u16* __restrict__ xb,
                                               const u16* __restrict__ w1t,
                                               const u16* __restrict__ w2t,
                                               const float* __restrict__ cw,
                                               int eidx,
                                               u16* __restrict__ hidden) {
  __shared__ alignas(16) u16 As[128 * 32];
  __shared__ alignas(16) u16 B1s[64 * 32];
  __shared__ alignas(16) u16 B2s[64 * 32];
  const int tid = threadIdx.x;
  const int w = tid >> 6, lane = tid & 63;
  const int wr = w >> 1, wc = w & 1;
  const int mBase = blockIdx.x * 128;
  const int nBase = blockIdx.y * 64;

  // staging: global_load_lds dest = uniform base + lane*16B  (linear layout)
  const int sr = w * 16 + (lane >> 2);         // 0..63
  const int sk = (lane & 3) * 8;
  const u16* gA0 = xb + (size_t)(mBase + sr) * DIM + sk;
  const u16* gA1 = gA0 + (size_t)64 * DIM;
  const u16* gB1 = w1t + (size_t)(nBase + sr) * DIM + sk;
  const u16* gB2 = w2t + (size_t)(nBase + sr) * DIM + sk;
  u16* lA0 = &As[sr * 32 + sk];
  u16* lA1 = &As[(64 + sr) * 32 + sk];
  u16* lB1 = &B1s[sr * 32 + sk];
  u16* lB2 = &B2s[sr * 32 + sk];

  f32x4 acc1[4][2], acc2[4][2];
  const f32x4 vz = {0.f, 0.f, 0.f, 0.f};
  #pragma unroll
  for (int m = 0; m < 4; m++)
    #pragma unroll
    for (int n = 0; n < 2; n++) { acc1[m][n] = vz; acc2[m][n] = vz; }

  const int ar = wr * 64 + (lane & 15);
  const int ak = (lane >> 4) * 8;
  const int br = wc * 32 + (lane & 15);

  for (int k0 = 0; k0 < DIM; k0 += 32) {
    GLDS16(gA0 + k0, lA0);
    GLDS16(gA1 + k0, lA1);
    GLDS16(gB1 + k0, lB1);
    GLDS16(gB2 + k0, lB2);
    __syncthreads();
    bf16x8 a[4], b1[2], b2[2];
    #pragma unroll
    for (int m = 0; m < 4; m++) a[m] = *(const bf16x8*)&As[(ar + m * 16) * 32 + ak];
    #pragma unroll
    for (int n = 0; n < 2; n++) {
      b1[n] = *(const bf16x8*)&B1s[(br + n * 16) * 32 + ak];
      b2[n] = *(const bf16x8*)&B2s[(br + n * 16) * 32 + ak];
    }
    #pragma unroll
    for (int m = 0; m < 4; m++)
      #pragma unroll
      for (int n = 0; n < 2; n++) {
        acc1[m][n] = __builtin_amdgcn_mfma_f32_16x16x32_bf16(a[m], b1[n], acc1[m][n], 0, 0, 0);
        acc2[m][n] = __builtin_amdgcn_mfma_f32_16x16x32_bf16(a[m], b2[n], acc2[m][n], 0, 0, 0);
      }
    __syncthreads();
  }

  // epilogue: D layout col=lane&15, row=(lane>>4)*4+r  [m89-verified]
  #pragma unroll
  for (int m = 0; m < 4; m++) {
    #pragma unroll
    for (int r = 0; r < 4; r++) {
      const int trow = mBase + wr * 64 + m * 16 + (lane >> 4) * 4 + r;
      const float c = cw[(size_t)trow * NEXP1 + eidx];
      #pragma unroll
      for (int n = 0; n < 2; n++) {
        const int hcol = nBase + wc * 32 + n * 16 + (lane & 15);
        const float v1 = acc1[m][n][r], v2 = acc2[m][n][r];
        const float h = (v1 / (1.f + __expf(-v1))) * v2 * c;
        hidden[(size_t)trow * HID + hcol] = f2bf(h);
      }
    }
  }
}

// ---------- gemm2: out (+)= hidden * proj ----------
// A = hidden [NTOK][HID], B^T rows = pjt [DIM][HID].  Same tiling, K=1536.
__global__ __launch_bounds__(256) void k_gemm2(const u16* __restrict__ hid,
                                               const u16* __restrict__ pjt,
                                               float* __restrict__ out, int init) {
  __shared__ alignas(16) u16 As[128 * 32];
  __shared__ alignas(16) u16 Bs[64 * 32];
  const int tid = threadIdx.x;
  const int w = tid >> 6, lane = tid & 63;
  const int wr = w >> 1, wc = w & 1;
  const int mBase = blockIdx.x * 128;
  const int nBase = blockIdx.y * 64;

  const int sr = w * 16 + (lane >> 2);
  const int sk = (lane & 3) * 8;
  const u16* gA0 = hid + (size_t)(mBase + sr) * HID + sk;
  const u16* gA1 = gA0 + (size_t)64 * HID;
  const u16* gB = pjt + (size_t)(nBase + sr) * HID + sk;
  u16* lA0 = &As[sr * 32 + sk];
  u16* lA1 = &As[(64 + sr) * 32 + sk];
  u16* lB = &Bs[sr * 32 + sk];

  f32x4 acc[4][2];
  const f32x4 vz = {0.f, 0.f, 0.f, 0.f};
  #pragma unroll
  for (int m = 0; m < 4; m++)
    #pragma unroll
    for (int n = 0; n < 2; n++) acc[m][n] = vz;

  const int ar = wr * 64 + (lane & 15);
  const int ak = (lane >> 4) * 8;
  const int br = wc * 32 + (lane & 15);

  for (int k0 = 0; k0 < HID; k0 += 32) {
    GLDS16(gA0 + k0, lA0);
    GLDS16(gA1 + k0, lA1);
    GLDS16(gB + k0, lB);
    __syncthreads();
    bf16x8 a[4], b[2];
    #pragma unroll
    for (int m = 0; m < 4; m++) a[m] = *(const bf16x8*)&As[(ar + m * 16) * 32 + ak];
    #pragma unroll
    for (int n = 0; n < 2; n++) b[n] = *(const bf16x8*)&Bs[(br + n * 16) * 32 + ak];
    #pragma unroll
    for (int m = 0; m < 4; m++)
      #pragma unroll
      for (int n = 0; n < 2; n++)
        acc[m][n] = __builtin_amdgcn_mfma_f32_16x16x32_bf16(a[m], b[n], acc[m][n], 0, 0, 0);
    __syncthreads();
  }

  #pragma unroll
  for (int m = 0; m < 4; m++)
    #pragma unroll
    for (int r = 0; r < 4; r++) {
      const int trow = mBase + wr * 64 + m * 16 + (lane >> 4) * 4 + r;
      #pragma unroll
      for (int n = 0; n < 2; n++) {
        const int dcol = nBase + wc * 32 + n * 16 + (lane & 15);
        const size_t idx = (size_t)trow * DIM + dcol;
        const float v = acc[m][n][r];
        if (init) out[idx] = v; else out[idx] += v;
      }
    }
}

// ---------- launch ----------
extern "C" void kernel_launch(void* const* d_in, const int* in_sizes, int n_in,
                              void* d_out, int out_size, void* d_ws, size_t ws_size,
                              hipStream_t stream) {
  const float* x     = (const float*)d_in[0];
  const float* rw    = (const float*)d_in[1];
  const float* sw1   = (const float*)d_in[2];
  const float* sw2   = (const float*)d_in[3];
  const float* sproj = (const float*)d_in[4];
  const float* ew1   = (const float*)d_in[5];
  const float* ew2   = (const float*)d_in[6];
  const float* eproj = (const float*)d_in[7];
  float* out   = (float*)d_out;
  float* probs = out + (size_t)NTOK * DIM;

  // workspace layout (bytes)
  constexpr size_t SL   = (size_t)HID * DIM;          // elems per expert weight slice
  constexpr size_t off_xb  = 0;                        // 6,291,456 B
  constexpr size_t off_w1t = 6291456;                  // 9 slices bf16
  constexpr size_t off_w2t = off_w1t + 2 * 9 * SL;     // 27,525,120
  constexpr size_t off_pjt = off_w2t + 2 * 9 * SL;     // 48,758,784
  constexpr size_t off_cw  = off_pjt + 2 * 9 * SL;     // 69,992,448
  constexpr size_t off_hid = off_cw + (size_t)NTOK * NEXP1 * 4;  // 70,139,904

  char* ws = (char*)d_ws;
  u16*   xb  = (u16*)(ws + off_xb);
  u16*   w1t = (u16*)(ws + off_w1t);
  u16*   w2t = (u16*)(ws + off_w2t);
  u16*   pjt = (u16*)(ws + off_pjt);
  float* cw  = (float*)(ws + off_cw);
  u16*   hid = (u16*)(ws + off_hid);

  // 1. conversions / transposes
  k_cvt_x<<<(NTOK * DIM / 4 + 255) / 256, 256, 0, stream>>>(x, xb, NTOK * DIM / 4);
  dim3 trb(32, 8);
  k_tr<<<dim3(HID / 32, DIM / 32, 8), trb, 0, stream>>>(ew1, w1t, DIM, HID);
  k_tr<<<dim3(HID / 32, DIM / 32, 1), trb, 0, stream>>>(sw1, w1t + 8 * SL, DIM, HID);
  k_tr<<<dim3(HID / 32, DIM / 32, 8), trb, 0, stream>>>(ew2, w2t, DIM, HID);
  k_tr<<<dim3(HID / 32, DIM / 32, 1), trb, 0, stream>>>(sw2, w2t + 8 * SL, DIM, HID);
  k_tr<<<dim3(DIM / 32, HID / 32, 8), trb, 0, stream>>>(eproj, pjt, HID, DIM);
  k_tr<<<dim3(DIM / 32, HID / 32, 1), trb, 0, stream>>>(sproj, pjt + 8 * SL, HID, DIM);

  // 2. router
  k_router<<<NTOK, 64, 0, stream>>>(x, rw, probs, cw);

  // 3. experts: 0..7 routed, 8 shared (cw[.,8]=1)
  for (int e = 0; e < NEXP1; ++e) {
    k_gemm1<<<dim3(NTOK / 128, HID / 64), 256, 0, stream>>>(
        xb, w1t + (size_t)e * SL, w2t + (size_t)e * SL, cw, e, hid);
    k_gemm2<<<dim3(NTOK / 128, DIM / 64), 256, 0, stream>>>(
        hid, pjt + (size_t)e * SL, out, e == 0 ? 1 : 0);
  }
}

// Round 2
// 437.613 us; speedup vs baseline: 1.5326x; 1.5326x over previous
//
#include <hip/hip_runtime.h>

typedef unsigned short u16;
typedef __bf16 bf16x8 __attribute__((ext_vector_type(8)));
typedef float f32x4 __attribute__((ext_vector_type(4)));

// ---------- helpers ----------
__device__ __forceinline__ u16 f2bf(float f) {
  union { float f; unsigned u; } v; v.f = f;
  return (u16)((v.u + 0x7fffu + ((v.u >> 16) & 1u)) >> 16);   // RNE
}

#define GLDS16(g, l)                                                          \
  __builtin_amdgcn_global_load_lds(                                           \
      (const __attribute__((address_space(1))) void*)(g),                     \
      (__attribute__((address_space(3))) void*)(l), 16, 0, 0)

// ---------- sizes ----------
#define NTOK 4096     // B*T
#define DIM  768
#define HID  1536
#define NEXP 8
#define CAPR 9216     // routed slot capacity (8192 + per-expert pad to 128)
#define SHB  9216     // shared-expert slot base
#define NSLOT 13312   // CAPR + NTOK
#define MAXT 104      // max M-tiles: <=71 routed + 32 shared

// ---------- f32 -> bf16 elementwise (x) ----------
__global__ __launch_bounds__(256) void k_cvt_x(const float* __restrict__ src,
                                               u16* __restrict__ dst, int n4) {
  const int i = blockIdx.x * 256 + threadIdx.x;
  if (i >= n4) return;
  const float4 v = ((const float4*)src)[i];
  ushort4 o;
  o.x = f2bf(v.x); o.y = f2bf(v.y); o.z = f2bf(v.z); o.w = f2bf(v.w);
  ((ushort4*)dst)[i] = o;
}

// ---------- batched transpose f32[R][C] -> bf16[C][R] ----------
__global__ __launch_bounds__(256) void k_tr(const float* __restrict__ src,
                                            u16* __restrict__ dst, int R, int C) {
  __shared__ u16 tile[32][33];
  const size_t bo = (size_t)blockIdx.z * R * C;
  src += bo; dst += bo;
  const int c0 = blockIdx.x * 32, r0 = blockIdx.y * 32;
  const int tx = threadIdx.x, ty = threadIdx.y;
  #pragma unroll
  for (int i = 0; i < 32; i += 8)
    tile[ty + i][tx] = f2bf(src[(size_t)(r0 + ty + i) * C + c0 + tx]);
  __syncthreads();
  #pragma unroll
  for (int i = 0; i < 32; i += 8)
    dst[(size_t)(c0 + ty + i) * R + r0 + tx] = tile[tx][ty + i];
}

// ---------- router: probs + top-2 (renormalized) ----------
__global__ __launch_bounds__(64) void k_router(const float* __restrict__ x,
                                               const float* __restrict__ rw,
                                               float* __restrict__ probs,
                                               int* __restrict__ topIdx,
                                               float* __restrict__ topW) {
  const int t = blockIdx.x;
  const int lane = threadIdx.x;
  const float* xr = x + (size_t)t * DIM;
  float acc[NEXP] = {0, 0, 0, 0, 0, 0, 0, 0};
  for (int d = lane; d < DIM; d += 64) {
    const float xv = xr[d];
    #pragma unroll
    for (int e = 0; e < NEXP; e++) acc[e] += xv * rw[e * DIM + d];
  }
  #pragma unroll
  for (int e = 0; e < NEXP; e++)
    #pragma unroll
    for (int s = 32; s > 0; s >>= 1) acc[e] += __shfl_xor(acc[e], s, 64);
  if (lane == 0) {
    float mx = acc[0];
    #pragma unroll
    for (int e = 1; e < NEXP; e++) mx = fmaxf(mx, acc[e]);
    float p[NEXP], sum = 0.f;
    #pragma unroll
    for (int e = 0; e < NEXP; e++) { p[e] = expf(acc[e] - mx); sum += p[e]; }
    const float inv = 1.f / sum;
    #pragma unroll
    for (int e = 0; e < NEXP; e++) p[e] *= inv;
    #pragma unroll
    for (int e = 0; e < NEXP; e++) probs[(size_t)t * NEXP + e] = p[e];
    int i1 = 0;
    #pragma unroll
    for (int e = 1; e < NEXP; e++) if (p[e] > p[i1]) i1 = e;
    int i2 = (i1 == 0) ? 1 : 0;
    #pragma unroll
    for (int e = 0; e < NEXP; e++) if (e != i1 && p[e] > p[i2]) i2 = e;
    const float s2 = 1.f / (p[i1] + p[i2]);
    topIdx[2 * t] = i1; topIdx[2 * t + 1] = i2;
    topW[2 * t] = p[i1] * s2; topW[2 * t + 1] = p[i2] * s2;
  }
}

// ---------- per-expert stable compaction (one block per expert) ----------
__global__ __launch_bounds__(256) void k_build(const int* __restrict__ topIdx,
                                               const float* __restrict__ topW,
                                               int* __restrict__ listT,
                                               float* __restrict__ listW,
                                               int* __restrict__ cnt) {
  const int e = blockIdx.x;
  const int tid = threadIdx.x, w = tid >> 6, lane = tid & 63;
  __shared__ int wt[4];
  int base = 0;
  for (int c = 0; c < NTOK / 256; ++c) {
    const int t = c * 256 + tid;
    const int i0 = topIdx[2 * t], i1 = topIdx[2 * t + 1];
    const int pr = (i0 == e) ? 1 : ((i1 == e) ? 2 : 0);
    const unsigned long long m = __ballot(pr != 0);
    const int wl = __popcll(m & ((1ull << lane) - 1ull));
    if (lane == 0) wt[w] = __popcll(m);
    __syncthreads();
    int wbase = 0;
    #pragma unroll
    for (int j = 0; j < 4; j++) if (j < w) wbase += wt[j];
    if (pr) {
      const int pos = base + wbase + wl;
      listT[e * NTOK + pos] = t;
      listW[e * NTOK + pos] = (pr == 1) ? topW[2 * t] : topW[2 * t + 1];
    }
    base += wt[0] + wt[1] + wt[2] + wt[3];
    __syncthreads();
  }
  if (tid == 0) cnt[e] = base;
}

// ---------- tile map + slot arrays ----------
__global__ __launch_bounds__(256) void k_tilemap(const int* __restrict__ cnt,
                                                 const int* __restrict__ listT,
                                                 const float* __restrict__ listW,
                                                 int* __restrict__ tileExp,
                                                 int* __restrict__ tileM0,
                                                 int* __restrict__ slotTok,
                                                 float* __restrict__ slotW) {
  __shared__ int offPad[NEXP + 1];
  __shared__ int cs[NEXP];
  const int tid = threadIdx.x;
  if (tid == 0) {
    int tt = 0, acc = 0;
    for (int e = 0; e < NEXP; e++) {
      cs[e] = cnt[e];
      offPad[e] = acc;
      const int tiles = (cs[e] + 127) >> 7;
      for (int i = 0; i < tiles; i++) { tileExp[tt] = e; tileM0[tt] = acc + i * 128; tt++; }
      acc += tiles * 128;
    }
    offPad[NEXP] = acc;
    for (int i = 0; i < NTOK / 128; i++) { tileExp[tt] = NEXP; tileM0[tt] = SHB + i * 128; tt++; }
    for (; tt < MAXT; tt++) tileExp[tt] = -1;
  }
  __syncthreads();
  for (int s = tid; s < CAPR; s += 256) {
    int tok = 0; float wv = 0.f;
    #pragma unroll
    for (int e = 0; e < NEXP; e++)
      if (s >= offPad[e] && s < offPad[e + 1]) {
        const int i = s - offPad[e];
        if (i < cs[e]) { tok = listT[e * NTOK + i]; wv = listW[e * NTOK + i]; }
      }
    slotTok[s] = tok; slotW[s] = wv;
  }
  for (int s = tid; s < NTOK; s += 256) { slotTok[SHB + s] = s; slotW[SHB + s] = 1.f; }
}

// ---------- gemm1 (fused over all experts): hid = bf16(w * silu(x w1) * (x w2)) ----------
// LDS k-slot-major: As[4][128][8], Bs[4][64][8] -> conflict-free ds_read_b128.
__global__ __launch_bounds__(256) void k_gemm1(const u16* __restrict__ xb,
                                               const u16* __restrict__ w1t,
                                               const u16* __restrict__ w2t,
                                               const int* __restrict__ tileExp,
                                               const int* __restrict__ tileM0,
                                               const int* __restrict__ slotTok,
                                               const float* __restrict__ slotW,
                                               u16* __restrict__ hidden) {
  __shared__ alignas(16) u16 As[4 * 128 * 8];
  __shared__ alignas(16) u16 B1s[4 * 64 * 8];
  __shared__ alignas(16) u16 B2s[4 * 64 * 8];
  const int e = tileExp[blockIdx.x];
  if (e < 0) return;
  const int m0 = tileM0[blockIdx.x];
  const int nBase = blockIdx.y * 64;
  constexpr size_t SL = (size_t)HID * DIM;
  const u16* w1 = w1t + (size_t)e * SL;
  const u16* w2 = w2t + (size_t)e * SL;
  const int tid = threadIdx.x, w = tid >> 6, lane = tid & 63;
  const int wr = w >> 1, wc = w & 1;

  // A staging: 512 chunks, chunk = kslot*128 + row
  const int c0 = w * 128 + lane, c1 = c0 + 64;
  const int tok0 = slotTok[m0 + (c0 & 127)];
  const int tok1 = slotTok[m0 + (c1 & 127)];
  const u16* gA0 = xb + (size_t)tok0 * DIM + (c0 >> 7) * 8;
  const u16* gA1 = xb + (size_t)tok1 * DIM + (c1 >> 7) * 8;
  u16* lA0 = &As[c0 * 8];
  u16* lA1 = &As[c1 * 8];
  // B staging: 256 chunks, chunk = kslot*64 + row; wave w -> kslot w, row = lane
  const u16* gB1 = w1 + (size_t)(nBase + lane) * DIM + w * 8;
  const u16* gB2 = w2 + (size_t)(nBase + lane) * DIM + w * 8;
  u16* lB1 = &B1s[(w * 64 + lane) * 8];
  u16* lB2 = &B2s[(w * 64 + lane) * 8];

  f32x4 acc1[4][2], acc2[4][2];
  const f32x4 vz = {0.f, 0.f, 0.f, 0.f};
  #pragma unroll
  for (int m = 0; m < 4; m++)
    #pragma unroll
    for (int n = 0; n < 2; n++) { acc1[m][n] = vz; acc2[m][n] = vz; }

  const int ar = wr * 64 + (lane & 15);
  const int aks = lane >> 4;
  const int br = wc * 32 + (lane & 15);

  for (int k0 = 0; k0 < DIM; k0 += 32) {
    GLDS16(gA0 + k0, lA0);
    GLDS16(gA1 + k0, lA1);
    GLDS16(gB1 + k0, lB1);
    GLDS16(gB2 + k0, lB2);
    __syncthreads();
    bf16x8 a[4], b1[2], b2[2];
    #pragma unroll
    for (int m = 0; m < 4; m++) a[m] = *(const bf16x8*)&As[(aks * 128 + ar + m * 16) * 8];
    #pragma unroll
    for (int n = 0; n < 2; n++) {
      b1[n] = *(const bf16x8*)&B1s[(aks * 64 + br + n * 16) * 8];
      b2[n] = *(const bf16x8*)&B2s[(aks * 64 + br + n * 16) * 8];
    }
    #pragma unroll
    for (int m = 0; m < 4; m++)
      #pragma unroll
      for (int n = 0; n < 2; n++) {
        acc1[m][n] = __builtin_amdgcn_mfma_f32_16x16x32_bf16(a[m], b1[n], acc1[m][n], 0, 0, 0);
        acc2[m][n] = __builtin_amdgcn_mfma_f32_16x16x32_bf16(a[m], b2[n], acc2[m][n], 0, 0, 0);
      }
    __syncthreads();
  }

  #pragma unroll
  for (int m = 0; m < 4; m++) {
    #pragma unroll
    for (int r = 0; r < 4; r++) {
      const int slot = m0 + wr * 64 + m * 16 + (lane >> 4) * 4 + r;
      const float c = slotW[slot];
      #pragma unroll
      for (int n = 0; n < 2; n++) {
        const int hcol = nBase + wc * 32 + n * 16 + (lane & 15);
        const float v1 = acc1[m][n][r], v2 = acc2[m][n][r];
        const float h = (v1 / (1.f + __expf(-v1))) * v2 * c;
        hidden[(size_t)slot * HID + hcol] = f2bf(h);
      }
    }
  }
}

// ---------- gemm2 (fused): out[tok] += hid[slot] * proj_e ----------
__global__ __launch_bounds__(256) void k_gemm2(const u16* __restrict__ hid,
                                               const u16* __restrict__ pjt,
                                               const int* __restrict__ tileExp,
                                               const int* __restrict__ tileM0,
                                               const int* __restrict__ slotTok,
                                               float* __restrict__ out) {
  __shared__ alignas(16) u16 As[4 * 128 * 8];
  __shared__ alignas(16) u16 Bs[4 * 64 * 8];
  const int e = tileExp[blockIdx.x];
  if (e < 0) return;
  const int m0 = tileM0[blockIdx.x];
  const int nBase = blockIdx.y * 64;
  constexpr size_t SL = (size_t)HID * DIM;
  const u16* pj = pjt + (size_t)e * SL;
  const int tid = threadIdx.x, w = tid >> 6, lane = tid & 63;
  const int wr = w >> 1, wc = w & 1;

  const int c0 = w * 128 + lane, c1 = c0 + 64;
  const u16* gA0 = hid + (size_t)(m0 + (c0 & 127)) * HID + (c0 >> 7) * 8;
  const u16* gA1 = hid + (size_t)(m0 + (c1 & 127)) * HID + (c1 >> 7) * 8;
  u16* lA0 = &As[c0 * 8];
  u16* lA1 = &As[c1 * 8];
  const u16* gB = pj + (size_t)(nBase + lane) * HID + w * 8;
  u16* lB = &Bs[(w * 64 + lane) * 8];

  f32x4 acc[4][2];
  const f32x4 vz = {0.f, 0.f, 0.f, 0.f};
  #pragma unroll
  for (int m = 0; m < 4; m++)
    #pragma unroll
    for (int n = 0; n < 2; n++) acc[m][n] = vz;

  const int ar = wr * 64 + (lane & 15);
  const int aks = lane >> 4;
  const int br = wc * 32 + (lane & 15);

  for (int k0 = 0; k0 < HID; k0 += 32) {
    GLDS16(gA0 + k0, lA0);
    GLDS16(gA1 + k0, lA1);
    GLDS16(gB + k0, lB);
    __syncthreads();
    bf16x8 a[4], b[2];
    #pragma unroll
    for (int m = 0; m < 4; m++) a[m] = *(const bf16x8*)&As[(aks * 128 + ar + m * 16) * 8];
    #pragma unroll
    for (int n = 0; n < 2; n++) b[n] = *(const bf16x8*)&Bs[(aks * 64 + br + n * 16) * 8];
    #pragma unroll
    for (int m = 0; m < 4; m++)
      #pragma unroll
      for (int n = 0; n < 2; n++)
        acc[m][n] = __builtin_amdgcn_mfma_f32_16x16x32_bf16(a[m], b[n], acc[m][n], 0, 0, 0);
    __syncthreads();
  }

  #pragma unroll
  for (int m = 0; m < 4; m++)
    #pragma unroll
    for (int r = 0; r < 4; r++) {
      const int slot = m0 + wr * 64 + m * 16 + (lane >> 4) * 4 + r;
      const int tok = slotTok[slot];
      #pragma unroll
      for (int n = 0; n < 2; n++) {
        const int dcol = nBase + wc * 32 + n * 16 + (lane & 15);
        atomicAdd(&out[(size_t)tok * DIM + dcol], acc[m][n][r]);
      }
    }
}

// ---------- launch ----------
extern "C" void kernel_launch(void* const* d_in, const int* in_sizes, int n_in,
                              void* d_out, int out_size, void* d_ws, size_t ws_size,
                              hipStream_t stream) {
  const float* x     = (const float*)d_in[0];
  const float* rw    = (const float*)d_in[1];
  const float* sw1   = (const float*)d_in[2];
  const float* sw2   = (const float*)d_in[3];
  const float* sproj = (const float*)d_in[4];
  const float* ew1   = (const float*)d_in[5];
  const float* ew2   = (const float*)d_in[6];
  const float* eproj = (const float*)d_in[7];
  float* out   = (float*)d_out;
  float* probs = out + (size_t)NTOK * DIM;

  constexpr size_t SL = (size_t)HID * DIM;             // elems per weight slice
  constexpr size_t off_xb   = 0;
  constexpr size_t off_w1t  = 6291456;
  constexpr size_t off_w2t  = off_w1t + 2 * 9 * SL;    // +21,233,664
  constexpr size_t off_pjt  = off_w2t + 2 * 9 * SL;
  constexpr size_t off_hid  = off_pjt + 2 * 9 * SL;    // 69,992,448
  constexpr size_t off_meta = off_hid + (size_t)NSLOT * HID * 2;  // 110,886,912

  char* ws = (char*)d_ws;
  u16*   xb   = (u16*)(ws + off_xb);
  u16*   w1t  = (u16*)(ws + off_w1t);
  u16*   w2t  = (u16*)(ws + off_w2t);
  u16*   pjt  = (u16*)(ws + off_pjt);
  u16*   hid  = (u16*)(ws + off_hid);
  char*  meta = ws + off_meta;
  int*   topIdx  = (int*)meta;                  // 8192 ints
  float* topW    = (float*)(meta + 32768);      // 8192 f32
  int*   listT   = (int*)(meta + 65536);        // 8*4096 ints
  float* listW   = (float*)(meta + 196608);     // 8*4096 f32
  int*   cnt     = (int*)(meta + 327680);       // 8 ints
  int*   tileExp = (int*)(meta + 327712);       // MAXT ints (padded)
  int*   tileM0  = (int*)(meta + 328224);
  int*   slotTok = (int*)(meta + 328736);       // NSLOT ints
  float* slotW   = (float*)(meta + 328736 + 4 * (size_t)NSLOT);

  hipMemsetAsync(d_out, 0, (size_t)out_size * 4, stream);

  k_cvt_x<<<(NTOK * DIM / 4 + 255) / 256, 256, 0, stream>>>(x, xb, NTOK * DIM / 4);
  dim3 trb(32, 8);
  k_tr<<<dim3(HID / 32, DIM / 32, 8), trb, 0, stream>>>(ew1, w1t, DIM, HID);
  k_tr<<<dim3(HID / 32, DIM / 32, 1), trb, 0, stream>>>(sw1, w1t + 8 * SL, DIM, HID);
  k_tr<<<dim3(HID / 32, DIM / 32, 8), trb, 0, stream>>>(ew2, w2t, DIM, HID);
  k_tr<<<dim3(HID / 32, DIM / 32, 1), trb, 0, stream>>>(sw2, w2t + 8 * SL, DIM, HID);
  k_tr<<<dim3(DIM / 32, HID / 32, 8), trb, 0, stream>>>(eproj, pjt, HID, DIM);
  k_tr<<<dim3(DIM / 32, HID / 32, 1), trb, 0, stream>>>(sproj, pjt + 8 * SL, HID, DIM);

  k_router<<<NTOK, 64, 0, stream>>>(x, rw, probs, topIdx, topW);
  k_build<<<NEXP, 256, 0, stream>>>(topIdx, topW, listT, listW, cnt);
  k_tilemap<<<1, 256, 0, stream>>>(cnt, listT, listW, tileExp, tileM0, slotTok, slotW);

  k_gemm1<<<dim3(MAXT, HID / 64), 256, 0, stream>>>(xb, w1t, w2t, tileExp, tileM0,
                                                    slotTok, slotW, hid);
  k_gemm2<<<dim3(MAXT, DIM / 64), 256, 0, stream>>>(hid, pjt, tileExp, tileM0,
                                                    slotTok, out);
}

// Round 3
// 333.468 us; speedup vs baseline: 2.0113x; 1.3123x over previous
//
#include <hip/hip_runtime.h>

typedef unsigned short u16;
typedef __bf16 bf16x8 __attribute__((ext_vector_type(8)));
typedef float f32x4 __attribute__((ext_vector_type(4)));

// ---------- helpers ----------
__device__ __forceinline__ u16 f2bf(float f) {
  union { float f; unsigned u; } v; v.f = f;
  return (u16)((v.u + 0x7fffu + ((v.u >> 16) & 1u)) >> 16);   // RNE
}

#define GLDS16(g, l)                                                          \
  __builtin_amdgcn_global_load_lds(                                           \
      (const __attribute__((address_space(1))) void*)(g),                     \
      (__attribute__((address_space(3))) void*)(l), 16, 0, 0)

// ---------- sizes ----------
#define NTOK 4096     // B*T
#define DIM  768
#define HID  1536
#define NEXP 8
#define CAPR 9216     // routed slot capacity (8192 + per-expert pad to 128)
#define SHB  9216     // shared-expert slot base
#define NSLOT 13312   // CAPR + NTOK
#define MAXT 104      // max M-tiles: <=72 routed + 32 shared

// ---------- f32 -> bf16 elementwise (x) ----------
__global__ __launch_bounds__(256) void k_cvt_x(const float* __restrict__ src,
                                               u16* __restrict__ dst, int n4) {
  const int i = blockIdx.x * 256 + threadIdx.x;
  if (i >= n4) return;
  const float4 v = ((const float4*)src)[i];
  ushort4 o;
  o.x = f2bf(v.x); o.y = f2bf(v.y); o.z = f2bf(v.z); o.w = f2bf(v.w);
  ((ushort4*)dst)[i] = o;
}

// ---------- batched transpose f32[R][C] -> bf16[C][R] ----------
__global__ __launch_bounds__(256) void k_tr(const float* __restrict__ src,
                                            u16* __restrict__ dst, int R, int C) {
  __shared__ u16 tile[32][33];
  const size_t bo = (size_t)blockIdx.z * R * C;
  src += bo; dst += bo;
  const int c0 = blockIdx.x * 32, r0 = blockIdx.y * 32;
  const int tx = threadIdx.x, ty = threadIdx.y;
  #pragma unroll
  for (int i = 0; i < 32; i += 8)
    tile[ty + i][tx] = f2bf(src[(size_t)(r0 + ty + i) * C + c0 + tx]);
  __syncthreads();
  #pragma unroll
  for (int i = 0; i < 32; i += 8)
    dst[(size_t)(c0 + ty + i) * R + r0 + tx] = tile[tx][ty + i];
}

// ---------- router: probs + top-2 (renormalized) ----------
__global__ __launch_bounds__(64) void k_router(const float* __restrict__ x,
                                               const float* __restrict__ rw,
                                               float* __restrict__ probs,
                                               int* __restrict__ topIdx,
                                               float* __restrict__ topW) {
  const int t = blockIdx.x;
  const int lane = threadIdx.x;
  const float* xr = x + (size_t)t * DIM;
  float acc[NEXP] = {0, 0, 0, 0, 0, 0, 0, 0};
  for (int d = lane; d < DIM; d += 64) {
    const float xv = xr[d];
    #pragma unroll
    for (int e = 0; e < NEXP; e++) acc[e] += xv * rw[e * DIM + d];
  }
  #pragma unroll
  for (int e = 0; e < NEXP; e++)
    #pragma unroll
    for (int s = 32; s > 0; s >>= 1) acc[e] += __shfl_xor(acc[e], s, 64);
  if (lane == 0) {
    float mx = acc[0];
    #pragma unroll
    for (int e = 1; e < NEXP; e++) mx = fmaxf(mx, acc[e]);
    float p[NEXP], sum = 0.f;
    #pragma unroll
    for (int e = 0; e < NEXP; e++) { p[e] = expf(acc[e] - mx); sum += p[e]; }
    const float inv = 1.f / sum;
    #pragma unroll
    for (int e = 0; e < NEXP; e++) p[e] *= inv;
    #pragma unroll
    for (int e = 0; e < NEXP; e++) probs[(size_t)t * NEXP + e] = p[e];
    int i1 = 0;
    #pragma unroll
    for (int e = 1; e < NEXP; e++) if (p[e] > p[i1]) i1 = e;
    int i2 = (i1 == 0) ? 1 : 0;
    #pragma unroll
    for (int e = 0; e < NEXP; e++) if (e != i1 && p[e] > p[i2]) i2 = e;
    const float s2 = 1.f / (p[i1] + p[i2]);
    topIdx[2 * t] = i1; topIdx[2 * t + 1] = i2;
    topW[2 * t] = p[i1] * s2; topW[2 * t + 1] = p[i2] * s2;
  }
}

// ---------- per-expert stable compaction (one block per expert) ----------
__global__ __launch_bounds__(256) void k_build(const int* __restrict__ topIdx,
                                               const float* __restrict__ topW,
                                               int* __restrict__ listT,
                                               float* __restrict__ listW,
                                               int* __restrict__ listP,
                                               int* __restrict__ cnt) {
  const int e = blockIdx.x;
  const int tid = threadIdx.x, w = tid >> 6, lane = tid & 63;
  __shared__ int wt[4];
  int base = 0;
  for (int c = 0; c < NTOK / 256; ++c) {
    const int t = c * 256 + tid;
    const int i0 = topIdx[2 * t], i1 = topIdx[2 * t + 1];
    const int pr = (i0 == e) ? 1 : ((i1 == e) ? 2 : 0);
    const unsigned long long m = __ballot(pr != 0);
    const int wl = __popcll(m & ((1ull << lane) - 1ull));
    if (lane == 0) wt[w] = __popcll(m);
    __syncthreads();
    int wbase = 0;
    #pragma unroll
    for (int j = 0; j < 4; j++) if (j < w) wbase += wt[j];
    if (pr) {
      const int pos = base + wbase + wl;
      listT[e * NTOK + pos] = t;
      listW[e * NTOK + pos] = (pr == 1) ? topW[2 * t] : topW[2 * t + 1];
      listP[e * NTOK + pos] = pr;
    }
    base += wt[0] + wt[1] + wt[2] + wt[3];
    __syncthreads();
  }
  if (tid == 0) cnt[e] = base;
}

// ---------- tile map + slot arrays + inverse token->slot map ----------
__global__ __launch_bounds__(256) void k_tilemap(const int* __restrict__ cnt,
                                                 const int* __restrict__ listT,
                                                 const float* __restrict__ listW,
                                                 const int* __restrict__ listP,
                                                 int* __restrict__ tileExp,
                                                 int* __restrict__ tileM0,
                                                 int* __restrict__ slotTok,
                                                 float* __restrict__ slotW,
                                                 int* __restrict__ tokSlot) {
  __shared__ int offPad[NEXP + 1];
  __shared__ int cs[NEXP];
  const int tid = threadIdx.x;
  if (tid == 0) {
    int tt = 0, acc = 0;
    for (int e = 0; e < NEXP; e++) {
      cs[e] = cnt[e];
      offPad[e] = acc;
      const int tiles = (cs[e] + 127) >> 7;
      for (int i = 0; i < tiles; i++) { tileExp[tt] = e; tileM0[tt] = acc + i * 128; tt++; }
      acc += tiles * 128;
    }
    offPad[NEXP] = acc;
    for (int i = 0; i < NTOK / 128; i++) { tileExp[tt] = NEXP; tileM0[tt] = SHB + i * 128; tt++; }
    for (; tt < MAXT; tt++) tileExp[tt] = -1;
  }
  __syncthreads();
  for (int s = tid; s < CAPR; s += 256) {
    int tok = 0; float wv = 0.f; int pp = 0;
    #pragma unroll
    for (int e = 0; e < NEXP; e++)
      if (s >= offPad[e] && s < offPad[e + 1]) {
        const int i = s - offPad[e];
        if (i < cs[e]) {
          tok = listT[e * NTOK + i];
          wv = listW[e * NTOK + i];
          pp = listP[e * NTOK + i];
        }
      }
    slotTok[s] = tok; slotW[s] = wv;
    if (pp) tokSlot[2 * tok + (pp - 1)] = s;   // deterministic: unique (tok,pp)
  }
  for (int s = tid; s < NTOK; s += 256) { slotTok[SHB + s] = s; slotW[SHB + s] = 1.f; }
}

// ---------- GEMM building blocks ----------
__device__ __forceinline__ void g1_stage(u16 (&A)[4096], u16 (&B1)[4096], u16 (&B2)[4096],
                                         const u16* gA0, const u16* gA1,
                                         const u16* gB1a, const u16* gB1b,
                                         const u16* gB2a, const u16* gB2b,
                                         int k0, int l0, int l1) {
  GLDS16(gA0 + k0, &A[l0]);  GLDS16(gA1 + k0, &A[l1]);
  GLDS16(gB1a + k0, &B1[l0]); GLDS16(gB1b + k0, &B1[l1]);
  GLDS16(gB2a + k0, &B2[l0]); GLDS16(gB2b + k0, &B2[l1]);
}

__device__ __forceinline__ void g1_step(const u16 (&A)[4096], const u16 (&B1)[4096],
                                        const u16 (&B2)[4096], int aoff, int boff,
                                        f32x4 (&acc1)[4][4], f32x4 (&acc2)[4][4]) {
  bf16x8 av[4], b1v[4], b2v[4];
  #pragma unroll
  for (int m = 0; m < 4; m++) av[m] = *(const bf16x8*)&A[aoff + m * 128];
  #pragma unroll
  for (int n = 0; n < 4; n++) {
    b1v[n] = *(const bf16x8*)&B1[boff + n * 128];
    b2v[n] = *(const bf16x8*)&B2[boff + n * 128];
  }
  #pragma unroll
  for (int m = 0; m < 4; m++)
    #pragma unroll
    for (int n = 0; n < 4; n++) {
      acc1[m][n] = __builtin_amdgcn_mfma_f32_16x16x32_bf16(av[m], b1v[n], acc1[m][n], 0, 0, 0);
      acc2[m][n] = __builtin_amdgcn_mfma_f32_16x16x32_bf16(av[m], b2v[n], acc2[m][n], 0, 0, 0);
    }
}

__device__ __forceinline__ void g2_stage(u16 (&A)[4096], u16 (&B)[4096],
                                         const u16* gA0, const u16* gA1,
                                         const u16* gBa, const u16* gBb,
                                         int k0, int l0, int l1) {
  GLDS16(gA0 + k0, &A[l0]); GLDS16(gA1 + k0, &A[l1]);
  GLDS16(gBa + k0, &B[l0]); GLDS16(gBb + k0, &B[l1]);
}

__device__ __forceinline__ void g2_step(const u16 (&A)[4096], const u16 (&B)[4096],
                                        int aoff, int boff, f32x4 (&acc)[4][4]) {
  bf16x8 av[4], bv[4];
  #pragma unroll
  for (int m = 0; m < 4; m++) av[m] = *(const bf16x8*)&A[aoff + m * 128];
  #pragma unroll
  for (int n = 0; n < 4; n++) bv[n] = *(const bf16x8*)&B[boff + n * 128];
  #pragma unroll
  for (int m = 0; m < 4; m++)
    #pragma unroll
    for (int n = 0; n < 4; n++)
      acc[m][n] = __builtin_amdgcn_mfma_f32_16x16x32_bf16(av[m], bv[n], acc[m][n], 0, 0, 0);
}

// ---------- gemm1 (fused, 128x128, dbuf): hid = bf16(w * silu(x w1) * (x w2)) ----------
__global__ __launch_bounds__(256, 2) void k_gemm1(const u16* __restrict__ xb,
                                                  const u16* __restrict__ w1t,
                                                  const u16* __restrict__ w2t,
                                                  const int* __restrict__ tileExp,
                                                  const int* __restrict__ tileM0,
                                                  const int* __restrict__ slotTok,
                                                  const float* __restrict__ slotW,
                                                  u16* __restrict__ hidden) {
  __shared__ alignas(16) u16 As[2][4096];
  __shared__ alignas(16) u16 B1s[2][4096];
  __shared__ alignas(16) u16 B2s[2][4096];
  const int e = tileExp[blockIdx.x];
  if (e < 0) return;
  const int m0 = tileM0[blockIdx.x];
  const int nBase = blockIdx.y * 128;
  constexpr size_t SL = (size_t)HID * DIM;
  const u16* w1 = w1t + (size_t)e * SL;
  const u16* w2 = w2t + (size_t)e * SL;
  const int tid = threadIdx.x, w = tid >> 6, lane = tid & 63;
  const int wr = w >> 1, wc = w & 1;

  // staging chunks: c = kslot*128 + row; per-wave contiguous (uniform + lane)
  const int c0 = w * 128 + lane, c1 = c0 + 64;
  const int tok0 = slotTok[m0 + (c0 & 127)];
  const int tok1 = slotTok[m0 + (c1 & 127)];
  const u16* gA0 = xb + (size_t)tok0 * DIM + (c0 >> 7) * 8;
  const u16* gA1 = xb + (size_t)tok1 * DIM + (c1 >> 7) * 8;
  const u16* gB1a = w1 + (size_t)(nBase + (c0 & 127)) * DIM + (c0 >> 7) * 8;
  const u16* gB1b = w1 + (size_t)(nBase + (c1 & 127)) * DIM + (c1 >> 7) * 8;
  const u16* gB2a = w2 + (size_t)(nBase + (c0 & 127)) * DIM + (c0 >> 7) * 8;
  const u16* gB2b = w2 + (size_t)(nBase + (c1 & 127)) * DIM + (c1 >> 7) * 8;
  const int l0 = c0 * 8, l1 = c1 * 8;

  f32x4 acc1[4][4], acc2[4][4];
  const f32x4 vz = {0.f, 0.f, 0.f, 0.f};
  #pragma unroll
  for (int m = 0; m < 4; m++)
    #pragma unroll
    for (int n = 0; n < 4; n++) { acc1[m][n] = vz; acc2[m][n] = vz; }

  const int aoff = ((lane >> 4) * 128 + wr * 64 + (lane & 15)) * 8;
  const int boff = ((lane >> 4) * 128 + wc * 64 + (lane & 15)) * 8;

  constexpr int NT = DIM / 32;   // 24 (even)
  g1_stage(As[0], B1s[0], B2s[0], gA0, gA1, gB1a, gB1b, gB2a, gB2b, 0, l0, l1);
  __syncthreads();
  for (int t = 0; t + 2 < NT; t += 2) {
    g1_stage(As[1], B1s[1], B2s[1], gA0, gA1, gB1a, gB1b, gB2a, gB2b, (t + 1) * 32, l0, l1);
    g1_step(As[0], B1s[0], B2s[0], aoff, boff, acc1, acc2);
    __syncthreads();
    g1_stage(As[0], B1s[0], B2s[0], gA0, gA1, gB1a, gB1b, gB2a, gB2b, (t + 2) * 32, l0, l1);
    g1_step(As[1], B1s[1], B2s[1], aoff, boff, acc1, acc2);
    __syncthreads();
  }
  g1_stage(As[1], B1s[1], B2s[1], gA0, gA1, gB1a, gB1b, gB2a, gB2b, (NT - 1) * 32, l0, l1);
  g1_step(As[0], B1s[0], B2s[0], aoff, boff, acc1, acc2);
  __syncthreads();
  g1_step(As[1], B1s[1], B2s[1], aoff, boff, acc1, acc2);

  #pragma unroll
  for (int m = 0; m < 4; m++)
    #pragma unroll
    for (int r = 0; r < 4; r++) {
      const int slot = m0 + wr * 64 + m * 16 + (lane >> 4) * 4 + r;
      const float cwv = slotW[slot];
      #pragma unroll
      for (int n = 0; n < 4; n++) {
        const int hcol = nBase + wc * 64 + n * 16 + (lane & 15);
        const float v1 = acc1[m][n][r], v2 = acc2[m][n][r];
        hidden[(size_t)slot * HID + hcol] = f2bf((v1 / (1.f + __expf(-v1))) * v2 * cwv);
      }
    }
}

// ---------- gemm2 (fused, 128x128, dbuf): g2[slot] = hid[slot] * proj_e  (no atomics) ----------
__global__ __launch_bounds__(256, 2) void k_gemm2(const u16* __restrict__ hid,
                                                  const u16* __restrict__ pjt,
                                                  const int* __restrict__ tileExp,
                                                  const int* __restrict__ tileM0,
                                                  float* __restrict__ g2) {
  __shared__ alignas(16) u16 As[2][4096];
  __shared__ alignas(16) u16 Bs[2][4096];
  const int e = tileExp[blockIdx.x];
  if (e < 0) return;
  const int m0 = tileM0[blockIdx.x];
  const int nBase = blockIdx.y * 128;
  constexpr size_t SL = (size_t)HID * DIM;
  const u16* pj = pjt + (size_t)e * SL;
  const int tid = threadIdx.x, w = tid >> 6, lane = tid & 63;
  const int wr = w >> 1, wc = w & 1;

  const int c0 = w * 128 + lane, c1 = c0 + 64;
  const u16* gA0 = hid + (size_t)(m0 + (c0 & 127)) * HID + (c0 >> 7) * 8;
  const u16* gA1 = hid + (size_t)(m0 + (c1 & 127)) * HID + (c1 >> 7) * 8;
  const u16* gBa = pj + (size_t)(nBase + (c0 & 127)) * HID + (c0 >> 7) * 8;
  const u16* gBb = pj + (size_t)(nBase + (c1 & 127)) * HID + (c1 >> 7) * 8;
  const int l0 = c0 * 8, l1 = c1 * 8;

  f32x4 acc[4][4];
  const f32x4 vz = {0.f, 0.f, 0.f, 0.f};
  #pragma unroll
  for (int m = 0; m < 4; m++)
    #pragma unroll
    for (int n = 0; n < 4; n++) acc[m][n] = vz;

  const int aoff = ((lane >> 4) * 128 + wr * 64 + (lane & 15)) * 8;
  const int boff = ((lane >> 4) * 128 + wc * 64 + (lane & 15)) * 8;

  constexpr int NT = HID / 32;   // 48 (even)
  g2_stage(As[0], Bs[0], gA0, gA1, gBa, gBb, 0, l0, l1);
  __syncthreads();
  for (int t = 0; t + 2 < NT; t += 2) {
    g2_stage(As[1], Bs[1], gA0, gA1, gBa, gBb, (t + 1) * 32, l0, l1);
    g2_step(As[0], Bs[0], aoff, boff, acc);
    __syncthreads();
    g2_stage(As[0], Bs[0], gA0, gA1, gBa, gBb, (t + 2) * 32, l0, l1);
    g2_step(As[1], Bs[1], aoff, boff, acc);
    __syncthreads();
  }
  g2_stage(As[1], Bs[1], gA0, gA1, gBa, gBb, (NT - 1) * 32, l0, l1);
  g2_step(As[0], Bs[0], aoff, boff, acc);
  __syncthreads();
  g2_step(As[1], Bs[1], aoff, boff, acc);

  #pragma unroll
  for (int m = 0; m < 4; m++)
    #pragma unroll
    for (int r = 0; r < 4; r++) {
      const int slot = m0 + wr * 64 + m * 16 + (lane >> 4) * 4 + r;
      #pragma unroll
      for (int n = 0; n < 4; n++) {
        const int dcol = nBase + wc * 64 + n * 16 + (lane & 15);
        g2[(size_t)slot * DIM + dcol] = acc[m][n][r];
      }
    }
}

// ---------- combine: out[t] = g2[minSlot] + g2[maxSlot] + g2[shared]  (deterministic) ----------
__global__ __launch_bounds__(192) void k_combine(const float* __restrict__ g2,
                                                 const int* __restrict__ tokSlot,
                                                 float* __restrict__ out) {
  const int t = blockIdx.x, d4 = threadIdx.x;
  const int sA = tokSlot[2 * t], sB = tokSlot[2 * t + 1];
  const int lo = sA < sB ? sA : sB;
  const int hi = sA < sB ? sB : sA;
  const float4 a = ((const float4*)(g2 + (size_t)lo * DIM))[d4];
  const float4 b = ((const float4*)(g2 + (size_t)hi * DIM))[d4];
  const float4 c = ((const float4*)(g2 + (size_t)(SHB + t) * DIM))[d4];
  float4 o;
  o.x = a.x + b.x + c.x; o.y = a.y + b.y + c.y;
  o.z = a.z + b.z + c.z; o.w = a.w + b.w + c.w;
  ((float4*)(out + (size_t)t * DIM))[d4] = o;
}

// ---------- launch ----------
extern "C" void kernel_launch(void* const* d_in, const int* in_sizes, int n_in,
                              void* d_out, int out_size, void* d_ws, size_t ws_size,
                              hipStream_t stream) {
  const float* x     = (const float*)d_in[0];
  const float* rw    = (const float*)d_in[1];
  const float* sw1   = (const float*)d_in[2];
  const float* sw2   = (const float*)d_in[3];
  const float* sproj = (const float*)d_in[4];
  const float* ew1   = (const float*)d_in[5];
  const float* ew2   = (const float*)d_in[6];
  const float* eproj = (const float*)d_in[7];
  float* out   = (float*)d_out;
  float* probs = out + (size_t)NTOK * DIM;

  constexpr size_t SL = (size_t)HID * DIM;
  constexpr size_t off_xb   = 0;
  constexpr size_t off_w1t  = 6291456;
  constexpr size_t off_w2t  = off_w1t + 2 * 9 * SL;
  constexpr size_t off_pjt  = off_w2t + 2 * 9 * SL;
  constexpr size_t off_hid  = off_pjt + 2 * 9 * SL;              // 69,992,448
  constexpr size_t off_g2   = off_hid + (size_t)NSLOT * HID * 2; // 110,886,912
  constexpr size_t off_meta = off_g2 + (size_t)NSLOT * DIM * 4;  // 151,781,376

  char* ws = (char*)d_ws;
  u16*   xb   = (u16*)(ws + off_xb);
  u16*   w1t  = (u16*)(ws + off_w1t);
  u16*   w2t  = (u16*)(ws + off_w2t);
  u16*   pjt  = (u16*)(ws + off_pjt);
  u16*   hid  = (u16*)(ws + off_hid);
  float* g2   = (float*)(ws + off_g2);
  char*  meta = ws + off_meta;
  int*   topIdx  = (int*)meta;                        // 32 KB
  float* topW    = (float*)(meta + 32768);            // 32 KB
  int*   listT   = (int*)(meta + 65536);              // 128 KB
  float* listW   = (float*)(meta + 196608);           // 128 KB
  int*   listP   = (int*)(meta + 327680);             // 128 KB
  int*   cnt     = (int*)(meta + 458752);
  int*   tileExp = (int*)(meta + 459264);
  int*   tileM0  = (int*)(meta + 459776);
  int*   slotTok = (int*)(meta + 460288);             // 52 KB
  float* slotW   = (float*)(meta + 513536);           // 52 KB
  int*   tokSlot = (int*)(meta + 566784);             // 32 KB

  k_cvt_x<<<(NTOK * DIM / 4 + 255) / 256, 256, 0, stream>>>(x, xb, NTOK * DIM / 4);
  dim3 trb(32, 8);
  k_tr<<<dim3(HID / 32, DIM / 32, 8), trb, 0, stream>>>(ew1, w1t, DIM, HID);
  k_tr<<<dim3(HID / 32, DIM / 32, 1), trb, 0, stream>>>(sw1, w1t + 8 * SL, DIM, HID);
  k_tr<<<dim3(HID / 32, DIM / 32, 8), trb, 0, stream>>>(ew2, w2t, DIM, HID);
  k_tr<<<dim3(HID / 32, DIM / 32, 1), trb, 0, stream>>>(sw2, w2t + 8 * SL, DIM, HID);
  k_tr<<<dim3(DIM / 32, HID / 32, 8), trb, 0, stream>>>(eproj, pjt, HID, DIM);
  k_tr<<<dim3(DIM / 32, HID / 32, 1), trb, 0, stream>>>(sproj, pjt + 8 * SL, HID, DIM);

  k_router<<<NTOK, 64, 0, stream>>>(x, rw, probs, topIdx, topW);
  k_build<<<NEXP, 256, 0, stream>>>(topIdx, topW, listT, listW, listP, cnt);
  k_tilemap<<<1, 256, 0, stream>>>(cnt, listT, listW, listP, tileExp, tileM0,
                                   slotTok, slotW, tokSlot);

  k_gemm1<<<dim3(MAXT, HID / 128), 256, 0, stream>>>(xb, w1t, w2t, tileExp, tileM0,
                                                     slotTok, slotW, hid);
  k_gemm2<<<dim3(MAXT, DIM / 128), 256, 0, stream>>>(hid, pjt, tileExp, tileM0, g2);
  k_combine<<<NTOK, 192, 0, stream>>>(g2, tokSlot, out);
}

// Round 4
// 302.330 us; speedup vs baseline: 2.2184x; 1.1030x over previous
//
#include <hip/hip_runtime.h>

typedef unsigned short u16;
typedef __bf16 bf16x8 __attribute__((ext_vector_type(8)));
typedef float f32x4 __attribute__((ext_vector_type(4)));

// ---------- helpers ----------
__device__ __forceinline__ u16 f2bf(float f) {
  union { float f; unsigned u; } v; v.f = f;
  return (u16)((v.u + 0x7fffu + ((v.u >> 16) & 1u)) >> 16);   // RNE
}

#define GLDS16(g, l)                                                          \
  __builtin_amdgcn_global_load_lds(                                           \
      (const __attribute__((address_space(1))) void*)(g),                     \
      (__attribute__((address_space(3))) void*)(l), 16, 0, 0)

#define SBAR()  __builtin_amdgcn_s_barrier()
#define SCHED() __builtin_amdgcn_sched_barrier(0)
#define VMCNT(n) asm volatile("s_waitcnt vmcnt(" #n ")" ::: "memory")

// ---------- sizes ----------
#define NTOK 4096     // B*T
#define DIM  768
#define HID  1536
#define NEXP 8
#define CAPR 9216     // routed slot capacity (8192 + per-expert pad to 128)
#define SHB  9216     // shared-expert slot base
#define NSLOT 13312   // CAPR + NTOK
#define MAXT 104      // max M-tiles: <=72 routed + 32 shared

// ---------- f32 -> bf16 elementwise (x) ----------
__global__ __launch_bounds__(256) void k_cvt_x(const float* __restrict__ src,
                                               u16* __restrict__ dst, int n4) {
  const int i = blockIdx.x * 256 + threadIdx.x;
  if (i >= n4) return;
  const float4 v = ((const float4*)src)[i];
  ushort4 o;
  o.x = f2bf(v.x); o.y = f2bf(v.y); o.z = f2bf(v.z); o.w = f2bf(v.w);
  ((ushort4*)dst)[i] = o;
}

// ---------- fused transpose: 27 slices f32[R][C] -> bf16[C][R], contiguous dst ----------
__global__ __launch_bounds__(256) void k_tr_all(const float* __restrict__ ew1,
                                                const float* __restrict__ sw1,
                                                const float* __restrict__ ew2,
                                                const float* __restrict__ sw2,
                                                const float* __restrict__ eproj,
                                                const float* __restrict__ sproj,
                                                u16* __restrict__ dstBase) {
  __shared__ u16 tile[32][33];
  constexpr size_t SL = (size_t)HID * DIM;
  const int z = blockIdx.z;
  const float* src;
  int R, C, bxx = blockIdx.x, byy = blockIdx.y;
  if (z < 9)       { src = (z < 8) ? ew1 + (size_t)z * SL : sw1; R = DIM; C = HID; }
  else if (z < 18) { const int q = z - 9;  src = (q < 8) ? ew2 + (size_t)q * SL : sw2; R = DIM; C = HID; }
  else             { const int q = z - 18; src = (q < 8) ? eproj + (size_t)q * SL : sproj;
                     R = HID; C = DIM; const int t = bxx; bxx = byy; byy = t; }
  u16* dst = dstBase + (size_t)z * SL;
  const int c0 = bxx * 32, r0 = byy * 32;
  const int tx = threadIdx.x, ty = threadIdx.y;
  #pragma unroll
  for (int i = 0; i < 32; i += 8)
    tile[ty + i][tx] = f2bf(src[(size_t)(r0 + ty + i) * C + c0 + tx]);
  __syncthreads();
  #pragma unroll
  for (int i = 0; i < 32; i += 8)
    dst[(size_t)(c0 + ty + i) * R + r0 + tx] = tile[tx][ty + i];
}

// ---------- router: probs + top-2 (renormalized) ----------
__global__ __launch_bounds__(64) void k_router(const float* __restrict__ x,
                                               const float* __restrict__ rw,
                                               float* __restrict__ probs,
                                               int* __restrict__ topIdx,
                                               float* __restrict__ topW) {
  const int t = blockIdx.x;
  const int lane = threadIdx.x;
  const float* xr = x + (size_t)t * DIM;
  float acc[NEXP] = {0, 0, 0, 0, 0, 0, 0, 0};
  for (int d = lane; d < DIM; d += 64) {
    const float xv = xr[d];
    #pragma unroll
    for (int e = 0; e < NEXP; e++) acc[e] += xv * rw[e * DIM + d];
  }
  #pragma unroll
  for (int e = 0; e < NEXP; e++)
    #pragma unroll
    for (int s = 32; s > 0; s >>= 1) acc[e] += __shfl_xor(acc[e], s, 64);
  if (lane == 0) {
    float mx = acc[0];
    #pragma unroll
    for (int e = 1; e < NEXP; e++) mx = fmaxf(mx, acc[e]);
    float p[NEXP], sum = 0.f;
    #pragma unroll
    for (int e = 0; e < NEXP; e++) { p[e] = expf(acc[e] - mx); sum += p[e]; }
    const float inv = 1.f / sum;
    #pragma unroll
    for (int e = 0; e < NEXP; e++) p[e] *= inv;
    #pragma unroll
    for (int e = 0; e < NEXP; e++) probs[(size_t)t * NEXP + e] = p[e];
    int i1 = 0;
    #pragma unroll
    for (int e = 1; e < NEXP; e++) if (p[e] > p[i1]) i1 = e;
    int i2 = (i1 == 0) ? 1 : 0;
    #pragma unroll
    for (int e = 0; e < NEXP; e++) if (e != i1 && p[e] > p[i2]) i2 = e;
    const float s2 = 1.f / (p[i1] + p[i2]);
    topIdx[2 * t] = i1; topIdx[2 * t + 1] = i2;
    topW[2 * t] = p[i1] * s2; topW[2 * t + 1] = p[i2] * s2;
  }
}

// ---------- per-expert stable compaction (one block per expert) ----------
__global__ __launch_bounds__(256) void k_build(const int* __restrict__ topIdx,
                                               const float* __restrict__ topW,
                                               int* __restrict__ listT,
                                               float* __restrict__ listW,
                                               int* __restrict__ listP,
                                               int* __restrict__ cnt) {
  const int e = blockIdx.x;
  const int tid = threadIdx.x, w = tid >> 6, lane = tid & 63;
  __shared__ int wt[4];
  int base = 0;
  for (int c = 0; c < NTOK / 256; ++c) {
    const int t = c * 256 + tid;
    const int i0 = topIdx[2 * t], i1 = topIdx[2 * t + 1];
    const int pr = (i0 == e) ? 1 : ((i1 == e) ? 2 : 0);
    const unsigned long long m = __ballot(pr != 0);
    const int wl = __popcll(m & ((1ull << lane) - 1ull));
    if (lane == 0) wt[w] = __popcll(m);
    __syncthreads();
    int wbase = 0;
    #pragma unroll
    for (int j = 0; j < 4; j++) if (j < w) wbase += wt[j];
    if (pr) {
      const int pos = base + wbase + wl;
      listT[e * NTOK + pos] = t;
      listW[e * NTOK + pos] = (pr == 1) ? topW[2 * t] : topW[2 * t + 1];
      listP[e * NTOK + pos] = pr;
    }
    base += wt[0] + wt[1] + wt[2] + wt[3];
    __syncthreads();
  }
  if (tid == 0) cnt[e] = base;
}

// ---------- tile map + slot arrays + inverse token->slot map ----------
__global__ __launch_bounds__(256) void k_tilemap(const int* __restrict__ cnt,
                                                 const int* __restrict__ listT,
                                                 const float* __restrict__ listW,
                                                 const int* __restrict__ listP,
                                                 int* __restrict__ tileExp,
                                                 int* __restrict__ tileM0,
                                                 int* __restrict__ slotTok,
                                                 float* __restrict__ slotW,
                                                 int* __restrict__ tokSlot) {
  __shared__ int offPad[NEXP + 1];
  __shared__ int cs[NEXP];
  const int tid = threadIdx.x;
  if (tid == 0) {
    int tt = 0, acc = 0;
    for (int e = 0; e < NEXP; e++) {
      cs[e] = cnt[e];
      offPad[e] = acc;
      const int tiles = (cs[e] + 127) >> 7;
      for (int i = 0; i < tiles; i++) { tileExp[tt] = e; tileM0[tt] = acc + i * 128; tt++; }
      acc += tiles * 128;
    }
    offPad[NEXP] = acc;
    for (int i = 0; i < NTOK / 128; i++) { tileExp[tt] = NEXP; tileM0[tt] = SHB + i * 128; tt++; }
    for (; tt < MAXT; tt++) tileExp[tt] = -1;
  }
  __syncthreads();
  for (int s = tid; s < CAPR; s += 256) {
    int tok = 0; float wv = 0.f; int pp = 0;
    #pragma unroll
    for (int e = 0; e < NEXP; e++)
      if (s >= offPad[e] && s < offPad[e + 1]) {
        const int i = s - offPad[e];
        if (i < cs[e]) {
          tok = listT[e * NTOK + i];
          wv = listW[e * NTOK + i];
          pp = listP[e * NTOK + i];
        }
      }
    slotTok[s] = tok; slotW[s] = wv;
    if (pp) tokSlot[2 * tok + (pp - 1)] = s;   // deterministic: unique (tok,pp)
  }
  for (int s = tid; s < NTOK; s += 256) { slotTok[SHB + s] = s; slotW[SHB + s] = 1.f; }
}

// ---------- gemm1 (fused, 128x128, 3-deep counted-vmcnt pipeline) ----------
__global__ __launch_bounds__(256, 2) void k_gemm1(const u16* __restrict__ xb,
                                                  const u16* __restrict__ w1t,
                                                  const u16* __restrict__ w2t,
                                                  const int* __restrict__ tileExp,
                                                  const int* __restrict__ tileM0,
                                                  const int* __restrict__ slotTok,
                                                  const float* __restrict__ slotW,
                                                  u16* __restrict__ hidden) {
  __shared__ alignas(16) u16 As[3][4096];
  __shared__ alignas(16) u16 B1s[3][4096];
  __shared__ alignas(16) u16 B2s[3][4096];
  // XCD-chunked bijective swizzle (nwg = 1248 = 8*156), M-tile-fastest order
  const int chunk = (MAXT * (HID / 128)) >> 3;
  const int bid = blockIdx.x;
  const int wgid = (bid & 7) * chunk + (bid >> 3);
  const int bx = wgid % MAXT;
  const int by = wgid / MAXT;
  const int e = tileExp[bx];
  if (e < 0) return;
  const int m0 = tileM0[bx];
  const int nBase = by * 128;
  constexpr size_t SL = (size_t)HID * DIM;
  const u16* w1 = w1t + (size_t)e * SL;
  const u16* w2 = w2t + (size_t)e * SL;
  const int tid = threadIdx.x, w = tid >> 6, lane = tid & 63;
  const int wr = w >> 1, wc = w & 1;

  // staging chunks: c = kslot*128 + row; per-wave contiguous (uniform + lane*16B)
  const int c0 = w * 128 + lane, c1 = c0 + 64;
  const int tok0 = slotTok[m0 + (c0 & 127)];
  const int tok1 = slotTok[m0 + (c1 & 127)];
  const u16* gA0 = xb + (size_t)tok0 * DIM + (c0 >> 7) * 8;
  const u16* gA1 = xb + (size_t)tok1 * DIM + (c1 >> 7) * 8;
  const u16* gB1a = w1 + (size_t)(nBase + (c0 & 127)) * DIM + (c0 >> 7) * 8;
  const u16* gB1b = w1 + (size_t)(nBase + (c1 & 127)) * DIM + (c1 >> 7) * 8;
  const u16* gB2a = w2 + (size_t)(nBase + (c0 & 127)) * DIM + (c0 >> 7) * 8;
  const u16* gB2b = w2 + (size_t)(nBase + (c1 & 127)) * DIM + (c1 >> 7) * 8;
  const int l0 = c0 * 8, l1 = c1 * 8;

  f32x4 acc1[4][4], acc2[4][4];
  const f32x4 vz = {0.f, 0.f, 0.f, 0.f};
  #pragma unroll
  for (int m = 0; m < 4; m++)
    #pragma unroll
    for (int n = 0; n < 4; n++) { acc1[m][n] = vz; acc2[m][n] = vz; }

  const int aoff = ((lane >> 4) * 128 + wr * 64 + (lane & 15)) * 8;
  const int boff = ((lane >> 4) * 128 + wc * 64 + (lane & 15)) * 8;

#define G1_STAGE(buf, kk) do {                                                \
    GLDS16(gA0  + (kk), &As[buf][l0]);  GLDS16(gA1  + (kk), &As[buf][l1]);    \
    GLDS16(gB1a + (kk), &B1s[buf][l0]); GLDS16(gB1b + (kk), &B1s[buf][l1]);   \
    GLDS16(gB2a + (kk), &B2s[buf][l0]); GLDS16(gB2b + (kk), &B2s[buf][l1]);   \
  } while (0)

#define G1_BODY(buf, vm, dostage, kk) do {                                    \
    SCHED(); VMCNT(vm); SBAR(); SCHED();                                      \
    bf16x8 av[4], b1v[4], b2v[4];                                             \
    _Pragma("unroll")                                                         \
    for (int m = 0; m < 4; m++) av[m] = *(const bf16x8*)&As[buf][aoff + m * 128]; \
    _Pragma("unroll")                                                         \
    for (int n = 0; n < 4; n++) {                                             \
      b1v[n] = *(const bf16x8*)&B1s[buf][boff + n * 128];                     \
      b2v[n] = *(const bf16x8*)&B2s[buf][boff + n * 128];                     \
    }                                                                         \
    __builtin_amdgcn_s_setprio(1);                                            \
    _Pragma("unroll")                                                         \
    for (int m = 0; m < 4; m++)                                               \
      _Pragma("unroll")                                                       \
      for (int n = 0; n < 4; n++) {                                           \
        acc1[m][n] = __builtin_amdgcn_mfma_f32_16x16x32_bf16(av[m], b1v[n], acc1[m][n], 0, 0, 0); \
        acc2[m][n] = __builtin_amdgcn_mfma_f32_16x16x32_bf16(av[m], b2v[n], acc2[m][n], 0, 0, 0); \
      }                                                                       \
    __builtin_amdgcn_s_setprio(0);                                            \
    SCHED(); SBAR(); SCHED();                                                 \
    if (dostage) { G1_STAGE(buf, kk); }                                       \
  } while (0)

  constexpr int NT = DIM / 32;   // 24, divisible by 3
  G1_STAGE(0, 0);  SCHED();
  G1_STAGE(1, 32); SCHED();
  G1_STAGE(2, 64); SCHED();
  for (int t = 0; t < NT - 3; t += 3) {
    G1_BODY(0, 12, true, (t + 3) * 32);
    G1_BODY(1, 12, true, (t + 4) * 32);
    G1_BODY(2, 12, true, (t + 5) * 32);
  }
  G1_BODY(0, 12, false, 0);
  G1_BODY(1, 6,  false, 0);
  G1_BODY(2, 0,  false, 0);
#undef G1_BODY
#undef G1_STAGE

  #pragma unroll
  for (int m = 0; m < 4; m++)
    #pragma unroll
    for (int r = 0; r < 4; r++) {
      const int slot = m0 + wr * 64 + m * 16 + (lane >> 4) * 4 + r;
      const float cwv = slotW[slot];
      #pragma unroll
      for (int n = 0; n < 4; n++) {
        const int hcol = nBase + wc * 64 + n * 16 + (lane & 15);
        const float v1 = acc1[m][n][r], v2 = acc2[m][n][r];
        hidden[(size_t)slot * HID + hcol] = f2bf((v1 / (1.f + __expf(-v1))) * v2 * cwv);
      }
    }
}

// ---------- gemm2 (fused, 128x128, 3-deep counted-vmcnt pipeline, no atomics) ----------
__global__ __launch_bounds__(256, 3) void k_gemm2(const u16* __restrict__ hid,
                                                  const u16* __restrict__ pjt,
                                                  const int* __restrict__ tileExp,
                                                  const int* __restrict__ tileM0,
                                                  float* __restrict__ g2) {
  __shared__ alignas(16) u16 As[3][4096];
  __shared__ alignas(16) u16 Bs[3][4096];
  const int chunk = (MAXT * (DIM / 128)) >> 3;   // 624/8 = 78
  const int bid = blockIdx.x;
  const int wgid = (bid & 7) * chunk + (bid >> 3);
  const int bx = wgid % MAXT;
  const int by = wgid / MAXT;
  const int e = tileExp[bx];
  if (e < 0) return;
  const int m0 = tileM0[bx];
  const int nBase = by * 128;
  constexpr size_t SL = (size_t)HID * DIM;
  const u16* pj = pjt + (size_t)e * SL;
  const int tid = threadIdx.x, w = tid >> 6, lane = tid & 63;
  const int wr = w >> 1, wc = w & 1;

  const int c0 = w * 128 + lane, c1 = c0 + 64;
  const u16* gA0 = hid + (size_t)(m0 + (c0 & 127)) * HID + (c0 >> 7) * 8;
  const u16* gA1 = hid + (size_t)(m0 + (c1 & 127)) * HID + (c1 >> 7) * 8;
  const u16* gBa = pj + (size_t)(nBase + (c0 & 127)) * HID + (c0 >> 7) * 8;
  const u16* gBb = pj + (size_t)(nBase + (c1 & 127)) * HID + (c1 >> 7) * 8;
  const int l0 = c0 * 8, l1 = c1 * 8;

  f32x4 acc[4][4];
  const f32x4 vz = {0.f, 0.f, 0.f, 0.f};
  #pragma unroll
  for (int m = 0; m < 4; m++)
    #pragma unroll
    for (int n = 0; n < 4; n++) acc[m][n] = vz;

  const int aoff = ((lane >> 4) * 128 + wr * 64 + (lane & 15)) * 8;
  const int boff = ((lane >> 4) * 128 + wc * 64 + (lane & 15)) * 8;

#define G2_STAGE(buf, kk) do {                                                \
    GLDS16(gA0 + (kk), &As[buf][l0]); GLDS16(gA1 + (kk), &As[buf][l1]);       \
    GLDS16(gBa + (kk), &Bs[buf][l0]); GLDS16(gBb + (kk), &Bs[buf][l1]);       \
  } while (0)

#define G2_BODY(buf, vm, dostage, kk) do {                                    \
    SCHED(); VMCNT(vm); SBAR(); SCHED();                                      \
    bf16x8 av[4], bv[4];                                                      \
    _Pragma("unroll")                                                         \
    for (int m = 0; m < 4; m++) av[m] = *(const bf16x8*)&As[buf][aoff + m * 128]; \
    _Pragma("unroll")                                                         \
    for (int n = 0; n < 4; n++) bv[n] = *(const bf16x8*)&Bs[buf][boff + n * 128]; \
    __builtin_amdgcn_s_setprio(1);                                            \
    _Pragma("unroll")                                                         \
    for (int m = 0; m < 4; m++)                                               \
      _Pragma("unroll")                                                       \
      for (int n = 0; n < 4; n++)                                             \
        acc[m][n] = __builtin_amdgcn_mfma_f32_16x16x32_bf16(av[m], bv[n], acc[m][n], 0, 0, 0); \
    __builtin_amdgcn_s_setprio(0);                                            \
    SCHED(); SBAR(); SCHED();                                                 \
    if (dostage) { G2_STAGE(buf, kk); }                                       \
  } while (0)

  constexpr int NT = HID / 32;   // 48, divisible by 3
  G2_STAGE(0, 0);  SCHED();
  G2_STAGE(1, 32); SCHED();
  G2_STAGE(2, 64); SCHED();
  for (int t = 0; t < NT - 3; t += 3) {
    G2_BODY(0, 8, true, (t + 3) * 32);
    G2_BODY(1, 8, true, (t + 4) * 32);
    G2_BODY(2, 8, true, (t + 5) * 32);
  }
  G2_BODY(0, 8, false, 0);
  G2_BODY(1, 4, false, 0);
  G2_BODY(2, 0, false, 0);
#undef G2_BODY
#undef G2_STAGE

  #pragma unroll
  for (int m = 0; m < 4; m++)
    #pragma unroll
    for (int r = 0; r < 4; r++) {
      const int slot = m0 + wr * 64 + m * 16 + (lane >> 4) * 4 + r;
      #pragma unroll
      for (int n = 0; n < 4; n++) {
        const int dcol = nBase + wc * 64 + n * 16 + (lane & 15);
        g2[(size_t)slot * DIM + dcol] = acc[m][n][r];
      }
    }
}

// ---------- combine: out[t] = g2[minSlot] + g2[maxSlot] + g2[shared]  (deterministic) ----------
__global__ __launch_bounds__(192) void k_combine(const float* __restrict__ g2,
                                                 const int* __restrict__ tokSlot,
                                                 float* __restrict__ out) {
  const int t = blockIdx.x, d4 = threadIdx.x;
  const int sA = tokSlot[2 * t], sB = tokSlot[2 * t + 1];
  const int lo = sA < sB ? sA : sB;
  const int hi = sA < sB ? sB : sA;
  const float4 a = ((const float4*)(g2 + (size_t)lo * DIM))[d4];
  const float4 b = ((const float4*)(g2 + (size_t)hi * DIM))[d4];
  const float4 c = ((const float4*)(g2 + (size_t)(SHB + t) * DIM))[d4];
  float4 o;
  o.x = a.x + b.x + c.x; o.y = a.y + b.y + c.y;
  o.z = a.z + b.z + c.z; o.w = a.w + b.w + c.w;
  ((float4*)(out + (size_t)t * DIM))[d4] = o;
}

// ---------- launch ----------
extern "C" void kernel_launch(void* const* d_in, const int* in_sizes, int n_in,
                              void* d_out, int out_size, void* d_ws, size_t ws_size,
                              hipStream_t stream) {
  const float* x     = (const float*)d_in[0];
  const float* rw    = (const float*)d_in[1];
  const float* sw1   = (const float*)d_in[2];
  const float* sw2   = (const float*)d_in[3];
  const float* sproj = (const float*)d_in[4];
  const float* ew1   = (const float*)d_in[5];
  const float* ew2   = (const float*)d_in[6];
  const float* eproj = (const float*)d_in[7];
  float* out   = (float*)d_out;
  float* probs = out + (size_t)NTOK * DIM;

  constexpr size_t SL = (size_t)HID * DIM;
  constexpr size_t off_xb   = 0;
  constexpr size_t off_w1t  = 6291456;
  constexpr size_t off_w2t  = off_w1t + 2 * 9 * SL;
  constexpr size_t off_pjt  = off_w2t + 2 * 9 * SL;
  constexpr size_t off_hid  = off_pjt + 2 * 9 * SL;              // 69,992,448
  constexpr size_t off_g2   = off_hid + (size_t)NSLOT * HID * 2; // 110,886,912
  constexpr size_t off_meta = off_g2 + (size_t)NSLOT * DIM * 4;  // 151,781,376

  char* ws = (char*)d_ws;
  u16*   xb   = (u16*)(ws + off_xb);
  u16*   w1t  = (u16*)(ws + off_w1t);
  u16*   w2t  = (u16*)(ws + off_w2t);
  u16*   pjt  = (u16*)(ws + off_pjt);
  u16*   hid  = (u16*)(ws + off_hid);
  float* g2   = (float*)(ws + off_g2);
  char*  meta = ws + off_meta;
  int*   topIdx  = (int*)meta;                        // 32 KB
  float* topW    = (float*)(meta + 32768);            // 32 KB
  int*   listT   = (int*)(meta + 65536);              // 128 KB
  float* listW   = (float*)(meta + 196608);           // 128 KB
  int*   listP   = (int*)(meta + 327680);             // 128 KB
  int*   cnt     = (int*)(meta + 458752);
  int*   tileExp = (int*)(meta + 459264);
  int*   tileM0  = (int*)(meta + 459776);
  int*   slotTok = (int*)(meta + 460288);             // 52 KB
  float* slotW   = (float*)(meta + 513536);           // 52 KB
  int*   tokSlot = (int*)(meta + 566784);             // 32 KB

  k_cvt_x<<<(NTOK * DIM / 4 + 255) / 256, 256, 0, stream>>>(x, xb, NTOK * DIM / 4);
  k_tr_all<<<dim3(HID / 32, DIM / 32, 27), dim3(32, 8), 0, stream>>>(
      ew1, sw1, ew2, sw2, eproj, sproj, w1t);

  k_router<<<NTOK, 64, 0, stream>>>(x, rw, probs, topIdx, topW);
  k_build<<<NEXP, 256, 0, stream>>>(topIdx, topW, listT, listW, listP, cnt);
  k_tilemap<<<1, 256, 0, stream>>>(cnt, listT, listW, listP, tileExp, tileM0,
                                   slotTok, slotW, tokSlot);

  k_gemm1<<<MAXT * (HID / 128), 256, 0, stream>>>(xb, w1t, w2t, tileExp, tileM0,
                                                  slotTok, slotW, hid);
  k_gemm2<<<MAXT * (DIM / 128), 256, 0, stream>>>(hid, pjt, tileExp, tileM0, g2);
  k_combine<<<NTOK, 192, 0, stream>>>(g2, tokSlot, out);
}